// Round 10
// baseline (489.097 us; speedup 1.0000x reference)
//
#include <hip/hip_runtime.h>

#define BB 1024
#define TT 200

typedef __attribute__((ext_vector_type(8))) short short8;
typedef __attribute__((ext_vector_type(2))) short short2v;
typedef __attribute__((ext_vector_type(4))) float f32x4;

__device__ __forceinline__ float sigmoidf_(float x) { return __fdividef(1.0f, 1.0f + __expf(-x)); }
__device__ __forceinline__ float tanh_fast(float x) {
    x = fminf(15.f, fmaxf(-15.f, x));
    float e = __expf(-2.f * x);
    return __fdividef(1.f - e, 1.f + e);
}
__device__ __forceinline__ float dicef_(float x, float m, float v) {
    return x * sigmoidf_((x - m) * rsqrtf(v + 1e-9f));
}
__device__ __forceinline__ unsigned short f2bf(float f) {
    unsigned u = __float_as_uint(f);
    unsigned r = u + 0x7fffu + ((u >> 16) & 1u);
    return (unsigned short)(r >> 16);
}
__device__ __forceinline__ float bf2f(unsigned short h) {
    return __uint_as_float(((unsigned)h) << 16);
}
__device__ __forceinline__ unsigned cvt_pk_bf16(float lo, float hi) {
    unsigned r;
    asm("v_cvt_pk_bf16_f32 %0, %1, %2" : "=v"(r) : "v"(lo), "v"(hi));
    return r;
}
union U8 { short8 s8; unsigned u[4]; };

// dot of two bf16 pairs accumulating into f32
#if __has_builtin(__builtin_amdgcn_fdot2_f32_bf16)
__device__ __forceinline__ float dot2bf(unsigned h2, unsigned u2, float c) {
    union { unsigned u; short2v s; } A, B;
    A.u = h2; B.u = u2;
    return __builtin_amdgcn_fdot2_f32_bf16(A.s, B.s, c, false);
}
#else
__device__ __forceinline__ float dot2bf(unsigned h2, unsigned u2, float c) {
    float h0 = __uint_as_float(h2 << 16), h1 = __uint_as_float(h2 & 0xffff0000u);
    float u0 = __uint_as_float(u2 << 16), u1 = __uint_as_float(u2 & 0xffff0000u);
    return fmaf(h1, u1, fmaf(h0, u0, c));
}
#endif

// ---------------------------------------------------------------------------
// k_prep
// ---------------------------------------------------------------------------
__global__ void k_prep(const float* __restrict__ dense, const int* __restrict__ sparse,
                       const int* __restrict__ item_idx, const float* __restrict__ table,
                       const float* __restrict__ other_tables,
                       float* __restrict__ target, float* __restrict__ other) {
    int b = blockIdx.x, l = threadIdx.x;  // 64 threads
    target[b * 64 + l] = table[(size_t)item_idx[b] * 64 + l];
    if (l < 4) other[b * 36 + l] = dense[b * 4 + l];
    else if (l < 20) other[b * 36 + l] = other_tables[(size_t)sparse[b * 2 + 0] * 16 + (l - 4)];
    else if (l < 36) other[b * 36 + l] = other_tables[1000 * 16 + (size_t)sparse[b * 2 + 1] * 16 + (l - 20)];
}

// ---------------------------------------------------------------------------
// k_xw: XW = X @ W + bias, bf16 MFMA, masked-tile skip (unchanged)
// ---------------------------------------------------------------------------
template <int GATHER>
__global__ __launch_bounds__(256, 1) void k_xw(
    const int* __restrict__ idx, const float* __restrict__ tablef,
    const unsigned short* __restrict__ Abf,
    const float* __restrict__ W, const float* __restrict__ bias,
    const int* __restrict__ hist_len,
    unsigned short* __restrict__ out, int Mtiles, int tilestride)
{
    const int l = threadIdx.x & 63;
    const int wv = threadIdx.x >> 6;
    const int lg = l >> 4;
    const int li = l & 15;

    short8 bfr[12][2];
    float bn[12];
#pragma unroll
    for (int nt = 0; nt < 12; ++nt) {
        bn[nt] = bias[nt * 16 + li];
#pragma unroll
        for (int c = 0; c < 2; ++c) {
#pragma unroll
            for (int j = 0; j < 8; ++j) {
                int k = c * 32 + lg * 8 + j;
                bfr[nt][c][j] = (short)f2bf(W[k * 192 + nt * 16 + li]);
            }
        }
    }

    for (int tile = blockIdx.x * 4 + wv; tile < Mtiles; tile += tilestride) {
        long row = (long)tile * 16 + li;
        {
            int bb = (int)(row / TT);
            int tt = (int)(row - (long)bb * TT);
            int vld = (tt < hist_len[bb]) ? 1 : 0;
            if (__ballot(vld) == 0ull) continue;
        }

        short8 a[2];
        if (GATHER) {
            long id = idx[row];
            const float* tp = tablef + id * 64 + lg * 8;
#pragma unroll
            for (int c = 0; c < 2; ++c) {
                f32x4 v0 = *(const f32x4*)(tp + c * 32);
                f32x4 v1 = *(const f32x4*)(tp + c * 32 + 4);
#pragma unroll
                for (int j = 0; j < 4; ++j) {
                    a[c][j] = (short)f2bf(v0[j]);
                    a[c][4 + j] = (short)f2bf(v1[j]);
                }
            }
        } else {
#pragma unroll
            for (int c = 0; c < 2; ++c)
                a[c] = *(const short8*)(Abf + row * 64 + c * 32 + lg * 8);
        }

        f32x4 acc[12];
#pragma unroll
        for (int nt = 0; nt < 12; ++nt) acc[nt] = (f32x4){0.f, 0.f, 0.f, 0.f};
#pragma unroll
        for (int c = 0; c < 2; ++c)
#pragma unroll
            for (int nt = 0; nt < 12; ++nt)
                acc[nt] = __builtin_amdgcn_mfma_f32_16x16x32_bf16(a[c], bfr[nt][c], acc[nt], 0, 0, 0);

#pragma unroll
        for (int nt = 0; nt < 12; ++nt)
#pragma unroll
            for (int j = 0; j < 4; ++j) {
                long orow = (long)tile * 16 + lg * 4 + j;
                out[orow * 192 + nt * 16 + li] = f2bf(acc[nt][j] + bn[nt]);
            }
    }
}

// ---------------------------------------------------------------------------
// k_scan9: recurrent h@U, ONE WAVE per batch row, zero barriers.
// amdgpu_waves_per_eu(1,1): sets the backend's occupancy TARGET to 1 wave/EU
// -> VGPR pressure budget 512 -> the scheduler stops sinking the U loads
// into the loop (the r3-r9 reload pathology; __launch_bounds__ min-waves
// alone never changed the target). U bf16-packed: 96 uints. xw prefetch
// 2 steps deep to cover ~900cy HBM latency under the now-short step.
// ---------------------------------------------------------------------------
template <int AUG>
__global__ __launch_bounds__(64, 1) __attribute__((amdgpu_waves_per_eu(1, 1)))
void k_scan9(
    const unsigned short* __restrict__ xw,   // (B*T,192) bf16
    const float* __restrict__ U,             // (64,192)
    const int* __restrict__ hist_len,
    const float* __restrict__ scores,        // (B,T)
    unsigned short* __restrict__ hout,       // (B,T,64) bf16 (GRU1)
    float* __restrict__ hfinal)              // (B,64) f32 (AUGRU)
{
    __shared__ unsigned hb[32];              // 64 bf16 h values as 32 pairs
    const int l = threadIdx.x;
    const int b = blockIdx.x;
    const int len = hist_len[b];

    // bf16-packed U columns for this lane's gate col l: pair kk = (k=2kk, 2kk+1)
    unsigned Uzp[32], Urp[32], Uhp[32];
#pragma unroll
    for (int kk = 0; kk < 32; ++kk) {
        Uzp[kk] = cvt_pk_bf16(U[(2 * kk) * 192 + l],       U[(2 * kk + 1) * 192 + l]);
        Urp[kk] = cvt_pk_bf16(U[(2 * kk) * 192 + 64 + l],  U[(2 * kk + 1) * 192 + 64 + l]);
        Uhp[kk] = cvt_pk_bf16(U[(2 * kk) * 192 + 128 + l], U[(2 * kk + 1) * 192 + 128 + l]);
    }

    const unsigned short* xwr = xw + (size_t)b * TT * 192;
    const float* scr = scores + (size_t)b * TT;
    unsigned short* hor = hout + (size_t)b * TT * 64;

    unsigned short* hbs = (unsigned short*)hb;
    float h = 0.f;
    hbs[l] = 0;   // bf16 zero

    // 2-deep prefetch of xw rows (+ scores); rows 0 and 1 always in-bounds (TT=200)
    unsigned short z0v = xwr[l], r0v = xwr[64 + l], h0v = xwr[128 + l];
    unsigned short z1v = xwr[192 + l], r1v = xwr[256 + l], h1v = xwr[320 + l];
    float s0v = AUG ? scr[0] : 0.f;
    float s1v = AUG ? scr[1] : 0.f;

    const uint4* H4 = (const uint4*)hb;

    for (int t = 0; t < len; ++t) {
        const unsigned short cz = z0v, cr = r0v, ch = h0v;
        const float cs = s0v;
        // shift pipeline and issue load for t+2 (covered by ~2 steps of compute)
        z0v = z1v; r0v = r1v; h0v = h1v; s0v = s1v;
        if (t + 2 < len) {
            const unsigned short* p = xwr + (size_t)(t + 2) * 192;
            z1v = p[l]; r1v = p[64 + l]; h1v = p[128 + l];
            if (AUG) s1v = scr[t + 2];
        }

        // h broadcast: 8 uniform b128 reads; 96 dot2 into 6 chains
        float az0 = 0.f, az1 = 0.f, ar0 = 0.f, ar1 = 0.f, ah0 = 0.f, ah1 = 0.f;
#pragma unroll
        for (int q = 0; q < 8; ++q) {
            uint4 hq = H4[q];
            az0 = dot2bf(hq.x, Uzp[4 * q + 0], az0);
            ar0 = dot2bf(hq.x, Urp[4 * q + 0], ar0);
            ah0 = dot2bf(hq.x, Uhp[4 * q + 0], ah0);
            az1 = dot2bf(hq.y, Uzp[4 * q + 1], az1);
            ar1 = dot2bf(hq.y, Urp[4 * q + 1], ar1);
            ah1 = dot2bf(hq.y, Uhp[4 * q + 1], ah1);
            az0 = dot2bf(hq.z, Uzp[4 * q + 2], az0);
            ar0 = dot2bf(hq.z, Urp[4 * q + 2], ar0);
            ah0 = dot2bf(hq.z, Uhp[4 * q + 2], ah0);
            az1 = dot2bf(hq.w, Uzp[4 * q + 3], az1);
            ar1 = dot2bf(hq.w, Urp[4 * q + 3], ar1);
            ah1 = dot2bf(hq.w, Uhp[4 * q + 3], ah1);
        }
        float azf = az0 + az1, arf = ar0 + ar1, ahf = ah0 + ah1;

        float zg = sigmoidf_(bf2f(cz) + azf);
        if (AUG) zg *= cs;
        float rg = sigmoidf_(bf2f(cr) + arf);
        float hv = tanh_fast(bf2f(ch) + rg * ahf);
        h = (1.f - zg) * h + zg * hv;

        const unsigned short hbf = f2bf(h);
        hbs[l] = hbf;  // may-alias this step's reads -> ordered; in-order DS pipe
        if (!AUG) hor[(size_t)t * 64 + l] = hbf;
    }

    if (AUG) {
        hfinal[(size_t)b * 64 + l] = h;
    } else {
        const unsigned short fro = f2bf(h);
        for (int t = len; t < TT; ++t) hor[(size_t)t * 64 + l] = fro;
    }
}

// ---------------------------------------------------------------------------
// k_att: bf16 MFMA attention + fused softmax, len-clipped tiles (unchanged)
// ---------------------------------------------------------------------------
__global__ __launch_bounds__(256, 2) void k_att(
    const float* __restrict__ target, const unsigned short* __restrict__ seq_hb,
    const float* __restrict__ W1, const float* __restrict__ b1,
    const float* __restrict__ W2, const float* __restrict__ b2,
    const float* __restrict__ W3, const float* __restrict__ b3,
    const int* __restrict__ hist_len, float* __restrict__ scores)
{
    __shared__ unsigned short W1f[8 * 4 * 64 * 8];  // frag layout, 32 KB
    __shared__ float a1s[4][16][68];
    __shared__ float logit_lds[208];
    __shared__ float red[8];

    const int tid = threadIdx.x;
    const int wv = tid >> 6, l = tid & 63;
    const int lg = l >> 4, li = l & 15;
    const int b = blockIdx.x;
    const int len = hist_len[b];

    if (tid < 208) logit_lds[tid] = -1e9f;
    for (int i = tid; i < 8 * 4 * 64 * 8; i += 256) {
        int j = i & 7, ll = (i >> 3) & 63, nt = (i >> 9) & 3, c = i >> 11;
        int k = c * 32 + (ll >> 4) * 8 + j;
        int col = nt * 16 + (ll & 15);
        W1f[i] = f2bf(W1[k * 64 + col]);
    }
    __syncthreads();

    short8 w1r[8][4];
    const short8* wf = (const short8*)W1f;
#pragma unroll
    for (int c = 0; c < 8; ++c)
#pragma unroll
        for (int nt = 0; nt < 4; ++nt)
            w1r[c][nt] = wf[(c * 4 + nt) * 64 + l];

    short8 w2r[2];
#pragma unroll
    for (int c = 0; c < 2; ++c) {
        U8 t8;
#pragma unroll
        for (int m = 0; m < 4; ++m) {
            int k0 = c * 32 + lg * 8 + 2 * m;
            t8.u[m] = cvt_pk_bf16(W2[k0 * 16 + li], W2[(k0 + 1) * 16 + li]);
        }
        w2r[c] = t8.s8;
    }

    float b1v[4];
#pragma unroll
    for (int nt = 0; nt < 4; ++nt) b1v[nt] = b1[nt * 16 + li];
    const float b2v = b2[li];
    const float w3v = W3[li];
    const float b3r = b3[0];

    const float* qp = target + (size_t)b * 64;
    float qf_lo[8], qf_hi[8];
#pragma unroll
    for (int j = 0; j < 8; ++j) { qf_lo[j] = qp[lg * 8 + j]; qf_hi[j] = qp[32 + lg * 8 + j]; }
    U8 q8l, q8h;
#pragma unroll
    for (int m = 0; m < 4; ++m) {
        q8l.u[m] = cvt_pk_bf16(qf_lo[2 * m], qf_lo[2 * m + 1]);
        q8h.u[m] = cvt_pk_bf16(qf_hi[2 * m], qf_hi[2 * m + 1]);
    }

    for (int mt = wv; mt * 16 < len; mt += 4) {
        const int t = mt * 16 + li;
        const int tld = (t < TT) ? t : TT - 1;
        const unsigned short* hp = seq_hb + ((size_t)b * TT + tld) * 64 + lg * 8;
        short8 h8l = *(const short8*)hp;
        short8 h8h = *(const short8*)(hp + 32);

        U8 d8l, d8h, m8l, m8h;
#pragma unroll
        for (int m = 0; m < 4; ++m) {
            float h0, h1, d0, d1, p0, p1;
            h0 = bf2f((unsigned short)h8l[2 * m]); h1 = bf2f((unsigned short)h8l[2 * m + 1]);
            d0 = qf_lo[2 * m] - h0; d1 = qf_lo[2 * m + 1] - h1;
            p0 = qf_lo[2 * m] * h0; p1 = qf_lo[2 * m + 1] * h1;
            d8l.u[m] = cvt_pk_bf16(d0, d1);
            m8l.u[m] = cvt_pk_bf16(p0, p1);
            h0 = bf2f((unsigned short)h8h[2 * m]); h1 = bf2f((unsigned short)h8h[2 * m + 1]);
            d0 = qf_hi[2 * m] - h0; d1 = qf_hi[2 * m + 1] - h1;
            p0 = qf_hi[2 * m] * h0; p1 = qf_hi[2 * m + 1] * h1;
            d8h.u[m] = cvt_pk_bf16(d0, d1);
            m8h.u[m] = cvt_pk_bf16(p0, p1);
        }

        f32x4 acc[4];
#pragma unroll
        for (int nt = 0; nt < 4; ++nt) acc[nt] = (f32x4){0.f, 0.f, 0.f, 0.f};
#pragma unroll
        for (int nt = 0; nt < 4; ++nt) {
            acc[nt] = __builtin_amdgcn_mfma_f32_16x16x32_bf16(q8l.s8, w1r[0][nt], acc[nt], 0, 0, 0);
            acc[nt] = __builtin_amdgcn_mfma_f32_16x16x32_bf16(q8h.s8, w1r[1][nt], acc[nt], 0, 0, 0);
            acc[nt] = __builtin_amdgcn_mfma_f32_16x16x32_bf16(h8l,    w1r[2][nt], acc[nt], 0, 0, 0);
            acc[nt] = __builtin_amdgcn_mfma_f32_16x16x32_bf16(h8h,    w1r[3][nt], acc[nt], 0, 0, 0);
            acc[nt] = __builtin_amdgcn_mfma_f32_16x16x32_bf16(d8l.s8, w1r[4][nt], acc[nt], 0, 0, 0);
            acc[nt] = __builtin_amdgcn_mfma_f32_16x16x32_bf16(d8h.s8, w1r[5][nt], acc[nt], 0, 0, 0);
            acc[nt] = __builtin_amdgcn_mfma_f32_16x16x32_bf16(m8l.s8, w1r[6][nt], acc[nt], 0, 0, 0);
            acc[nt] = __builtin_amdgcn_mfma_f32_16x16x32_bf16(m8h.s8, w1r[7][nt], acc[nt], 0, 0, 0);
        }

#pragma unroll
        for (int nt = 0; nt < 4; ++nt)
#pragma unroll
            for (int jj = 0; jj < 4; ++jj) {
                float v = acc[nt][jj] + b1v[nt];
                a1s[wv][lg * 4 + jj][nt * 16 + li] = (v > 0.f) ? v : 0.25f * v;
            }

        const float* arow = &a1s[wv][li][0];
        f32x4 acc2 = (f32x4){0.f, 0.f, 0.f, 0.f};
#pragma unroll
        for (int c2 = 0; c2 < 2; ++c2) {
            f32x4 v0 = *(const f32x4*)(arow + c2 * 32 + lg * 8);
            f32x4 v1 = *(const f32x4*)(arow + c2 * 32 + lg * 8 + 4);
            U8 a2f;
            a2f.u[0] = cvt_pk_bf16(v0[0], v0[1]);
            a2f.u[1] = cvt_pk_bf16(v0[2], v0[3]);
            a2f.u[2] = cvt_pk_bf16(v1[0], v1[1]);
            a2f.u[3] = cvt_pk_bf16(v1[2], v1[3]);
            acc2 = __builtin_amdgcn_mfma_f32_16x16x32_bf16(a2f.s8, w2r[c2], acc2, 0, 0, 0);
        }

#pragma unroll
        for (int jj = 0; jj < 4; ++jj) {
            float a2 = acc2[jj] + b2v;
            a2 = (a2 > 0.f) ? a2 : 0.25f * a2;
            float part = a2 * w3v;
            part += __shfl_xor(part, 1);
            part += __shfl_xor(part, 2);
            part += __shfl_xor(part, 4);
            part += __shfl_xor(part, 8);
            int tt = mt * 16 + lg * 4 + jj;
            if (li == 0 && tt < TT)
                logit_lds[tt] = (tt < len) ? (part + b3r) : -1e9f;
        }
    }
    __syncthreads();

    float v = (tid < TT) ? logit_lds[tid] : -1e30f;
    float m = v;
#pragma unroll
    for (int s = 1; s < 64; s <<= 1) m = fmaxf(m, __shfl_xor(m, s));
    if (l == 0) red[wv] = m;
    __syncthreads();
    m = fmaxf(fmaxf(red[0], red[1]), fmaxf(red[2], red[3]));
    float e = (tid < TT) ? __expf(v - m) : 0.f;
    float sum = e;
#pragma unroll
    for (int s = 1; s < 64; s <<= 1) sum += __shfl_xor(sum, s);
    if (l == 0) red[4 + wv] = sum;
    __syncthreads();
    float inv = __fdividef(1.f, red[4] + red[5] + red[6] + red[7]);
    if (tid < TT) scores[(size_t)b * TT + tid] = e * inv;
}

// ---------------------------------------------------------------------------
// FFN chain (tiny, unchanged)
// ---------------------------------------------------------------------------
__global__ __launch_bounds__(256) void k_fc1(const float* __restrict__ fin,
                                             const float* __restrict__ tgt,
                                             const float* __restrict__ oth,
                                             const float* __restrict__ Wt,
                                             const float* __restrict__ bvec,
                                             float* __restrict__ fout) {
    __shared__ float z0[164];
    int b = blockIdx.x, tid = threadIdx.x;
    if (tid < 64) z0[tid] = fin[b * 64 + tid];
    else if (tid < 128) z0[tid] = tgt[b * 64 + tid - 64];
    else if (tid < 164) z0[tid] = oth[b * 36 + tid - 128];
    __syncthreads();
    float acc = bvec[tid];
#pragma unroll 4
    for (int k = 0; k < 164; ++k) acc += z0[k] * Wt[k * 256 + tid];
    fout[(size_t)b * 256 + tid] = acc;
}

template <int F>
__global__ __launch_bounds__(256) void k_stats(const float* __restrict__ x, float* __restrict__ stat) {
    int c = blockIdx.x, tid = threadIdx.x;
    float s = 0.f, sq = 0.f;
    for (int i = tid; i < BB; i += 256) {
        float v = x[(size_t)i * F + c];
        s += v; sq += v * v;
    }
#pragma unroll
    for (int m = 1; m < 64; m <<= 1) { s += __shfl_xor(s, m); sq += __shfl_xor(sq, m); }
    __shared__ float rs[4], rq[4];
    if ((tid & 63) == 0) { rs[tid >> 6] = s; rq[tid >> 6] = sq; }
    __syncthreads();
    if (tid == 0) {
        float S = rs[0] + rs[1] + rs[2] + rs[3];
        float Q = rq[0] + rq[1] + rq[2] + rq[3];
        float mean = S * (1.f / BB);
        float var = Q * (1.f / BB) - mean * mean;
        stat[c] = mean;
        stat[F + c] = var;
    }
}

__global__ __launch_bounds__(256) void k_fc2(const float* __restrict__ f1,
                                             const float* __restrict__ st1,
                                             const float* __restrict__ Wt,
                                             const float* __restrict__ bvec,
                                             float* __restrict__ f2) {
    __shared__ float z[256];
    int b = blockIdx.x, tid = threadIdx.x;
    float x = f1[(size_t)b * 256 + tid];
    z[tid] = dicef_(x, st1[tid], st1[256 + tid]);
    __syncthreads();
    if (tid < 128) {
        float acc = bvec[tid];
#pragma unroll 4
        for (int k = 0; k < 256; ++k) acc += z[k] * Wt[k * 128 + tid];
        f2[(size_t)b * 128 + tid] = acc;
    }
}

__global__ __launch_bounds__(128) void k_fc3(const float* __restrict__ f2,
                                             const float* __restrict__ st2,
                                             const float* __restrict__ Wt,
                                             const float* __restrict__ bvec,
                                             float* __restrict__ f3) {
    __shared__ float z[128];
    int b = blockIdx.x, tid = threadIdx.x;
    float x = f2[(size_t)b * 128 + tid];
    z[tid] = dicef_(x, st2[tid], st2[128 + tid]);
    __syncthreads();
    if (tid < 64) {
        float acc = bvec[tid];
#pragma unroll 4
        for (int k = 0; k < 128; ++k) acc += z[k] * Wt[k * 64 + tid];
        f3[(size_t)b * 64 + tid] = acc;
    }
}

__global__ void k_out(const float* __restrict__ f3, const float* __restrict__ st3,
                      const float* __restrict__ outW, const float* __restrict__ outb,
                      float* __restrict__ out) {
    int b = blockIdx.x, l = threadIdx.x;  // 64 threads
    float x = f3[(size_t)b * 64 + l];
    float z = dicef_(x, st3[l], st3[64 + l]);
    float p = z * outW[l];
#pragma unroll
    for (int m = 1; m < 64; m <<= 1) p += __shfl_xor(p, m);
    if (l == 0) out[b] = sigmoidf_(p + outb[0]);
}

// ---------------------------------------------------------------------------
extern "C" void kernel_launch(void* const* d_in, const int* in_sizes, int n_in,
                              void* d_out, int out_size, void* d_ws, size_t ws_size,
                              hipStream_t stream) {
    const float* dense      = (const float*)d_in[0];
    const int*   sparse     = (const int*)d_in[1];
    const int*   seq_idx    = (const int*)d_in[2];
    const int*   item_idx   = (const int*)d_in[3];
    const int*   hist_len   = (const int*)d_in[4];
    const float* item_table = (const float*)d_in[5];
    const float* other_tab  = (const float*)d_in[6];
    const float* gru_W = (const float*)d_in[7];
    const float* gru_U = (const float*)d_in[8];
    const float* gru_b = (const float*)d_in[9];
    const float* aug_W = (const float*)d_in[10];
    const float* aug_U = (const float*)d_in[11];
    const float* aug_b = (const float*)d_in[12];
    const float* att_W1 = (const float*)d_in[13];
    const float* att_b1 = (const float*)d_in[14];
    const float* att_W2 = (const float*)d_in[15];
    const float* att_b2 = (const float*)d_in[16];
    const float* att_W3 = (const float*)d_in[17];
    const float* att_b3 = (const float*)d_in[18];
    const float* ffn_W1 = (const float*)d_in[19];
    const float* ffn_b1 = (const float*)d_in[20];
    const float* ffn_W2 = (const float*)d_in[21];
    const float* ffn_b2 = (const float*)d_in[22];
    const float* ffn_W3 = (const float*)d_in[23];
    const float* ffn_b3 = (const float*)d_in[24];
    const float* out_W  = (const float*)d_in[25];
    const float* out_b  = (const float*)d_in[26];

    float* wsf = (float*)d_ws;
    unsigned short* xwb   = (unsigned short*)(wsf);              // (B*T,192) bf16
    unsigned short* seqhb = (unsigned short*)(wsf + 19660800);   // (B,T,64) bf16
    float* scores = wsf + 26214400;            // B*T
    float* target = wsf + 26419200;            // B*64
    float* other  = wsf + 26484736;            // B*36
    float* finals = wsf + 26521600;            // B*64
    float* f1     = wsf + 26587136;            // B*256
    float* f2     = wsf + 26849280;            // B*128
    float* f3     = wsf + 26980352;            // B*64
    float* st1    = wsf + 27045888;            // 512
    float* st2    = wsf + 27046400;            // 256
    float* st3    = wsf + 27046656;            // 128

    float* dout = (float*)d_out;
    const int Mtiles = (BB * TT) / 16;  // 12800

    k_prep<<<BB, 64, 0, stream>>>(dense, sparse, item_idx, item_table, other_tab, target, other);

    // xw1 = gather(item_table, seq_idx) @ gru_W + gru_b  (bf16 MFMA, masked tiles skipped)
    k_xw<1><<<800, 256, 0, stream>>>(seq_idx, item_table, nullptr, gru_W, gru_b, hist_len, xwb, Mtiles, 3200);

    // GRU1 recurrence -> seq_h bf16 (B,T,64)   [1 wave/row, bf16 U resident]
    k_scan9<0><<<BB, 64, 0, stream>>>(xwb, gru_U, hist_len, scores, seqhb, finals);

    // attention MLP (MFMA) + fused softmax -> scores
    k_att<<<BB, 256, 0, stream>>>(target, seqhb, att_W1, att_b1, att_W2, att_b2,
                                  att_W3, att_b3, hist_len, scores);

    // xw2 = seq_h @ aug_W + aug_b  (bf16 MFMA, masked tiles skipped)
    k_xw<0><<<800, 256, 0, stream>>>(nullptr, nullptr, seqhb, aug_W, aug_b, hist_len, xwb, Mtiles, 3200);

    // AUGRU recurrence -> finals f32 (B,64)
    k_scan9<1><<<BB, 64, 0, stream>>>(xwb, aug_U, hist_len, scores, seqhb, finals);

    k_fc1<<<BB, 256, 0, stream>>>(finals, target, other, ffn_W1, ffn_b1, f1);
    k_stats<256><<<256, 256, 0, stream>>>(f1, st1);
    k_fc2<<<BB, 256, 0, stream>>>(f1, st1, ffn_W2, ffn_b2, f2);
    k_stats<128><<<128, 256, 0, stream>>>(f2, st2);
    k_fc3<<<BB, 128, 0, stream>>>(f2, st2, ffn_W3, ffn_b3, f3);
    k_stats<64><<<64, 256, 0, stream>>>(f3, st3);
    k_out<<<BB, 64, 0, stream>>>(f3, st3, out_W, out_b, dout);
}

// Round 11
// 406.731 us; speedup vs baseline: 1.2025x; 1.2025x over previous
//
#include <hip/hip_runtime.h>

#define BB 1024
#define TT 200

typedef __attribute__((ext_vector_type(8))) short short8;
typedef __attribute__((ext_vector_type(2))) short short2v;
typedef __attribute__((ext_vector_type(4))) float f32x4;

__device__ __forceinline__ float sigmoidf_(float x) { return __fdividef(1.0f, 1.0f + __expf(-x)); }
__device__ __forceinline__ float tanh_fast(float x) {
    x = fminf(15.f, fmaxf(-15.f, x));
    float e = __expf(-2.f * x);
    return __fdividef(1.f - e, 1.f + e);
}
__device__ __forceinline__ float dicef_(float x, float m, float v) {
    return x * sigmoidf_((x - m) * rsqrtf(v + 1e-9f));
}
__device__ __forceinline__ unsigned short f2bf(float f) {
    unsigned u = __float_as_uint(f);
    unsigned r = u + 0x7fffu + ((u >> 16) & 1u);
    return (unsigned short)(r >> 16);
}
__device__ __forceinline__ float bf2f(unsigned short h) {
    return __uint_as_float(((unsigned)h) << 16);
}
__device__ __forceinline__ unsigned cvt_pk_bf16(float lo, float hi) {
    unsigned r;
    asm("v_cvt_pk_bf16_f32 %0, %1, %2" : "=v"(r) : "v"(lo), "v"(hi));
    return r;
}
union U8 { short8 s8; unsigned u[4]; };

// dot of two bf16 pairs accumulating into f32
#if __has_builtin(__builtin_amdgcn_fdot2_f32_bf16)
__device__ __forceinline__ float dot2bf(unsigned h2, unsigned u2, float c) {
    union { unsigned u; short2v s; } A, B;
    A.u = h2; B.u = u2;
    return __builtin_amdgcn_fdot2_f32_bf16(A.s, B.s, c, false);
}
#else
__device__ __forceinline__ float dot2bf(unsigned h2, unsigned u2, float c) {
    float h0 = __uint_as_float(h2 << 16), h1 = __uint_as_float(h2 & 0xffff0000u);
    float u0 = __uint_as_float(u2 << 16), u1 = __uint_as_float(u2 & 0xffff0000u);
    return fmaf(h1, u1, fmaf(h0, u0, c));
}
#endif

// ---------------------------------------------------------------------------
// k_prep
// ---------------------------------------------------------------------------
__global__ void k_prep(const float* __restrict__ dense, const int* __restrict__ sparse,
                       const int* __restrict__ item_idx, const float* __restrict__ table,
                       const float* __restrict__ other_tables,
                       float* __restrict__ target, float* __restrict__ other) {
    int b = blockIdx.x, l = threadIdx.x;  // 64 threads
    target[b * 64 + l] = table[(size_t)item_idx[b] * 64 + l];
    if (l < 4) other[b * 36 + l] = dense[b * 4 + l];
    else if (l < 20) other[b * 36 + l] = other_tables[(size_t)sparse[b * 2 + 0] * 16 + (l - 4)];
    else if (l < 36) other[b * 36 + l] = other_tables[1000 * 16 + (size_t)sparse[b * 2 + 1] * 16 + (l - 20)];
}

// ---------------------------------------------------------------------------
// k_xw: XW = X @ W + bias, bf16 MFMA, masked-tile skip (unchanged)
// ---------------------------------------------------------------------------
template <int GATHER>
__global__ __launch_bounds__(256, 1) void k_xw(
    const int* __restrict__ idx, const float* __restrict__ tablef,
    const unsigned short* __restrict__ Abf,
    const float* __restrict__ W, const float* __restrict__ bias,
    const int* __restrict__ hist_len,
    unsigned short* __restrict__ out, int Mtiles, int tilestride)
{
    const int l = threadIdx.x & 63;
    const int wv = threadIdx.x >> 6;
    const int lg = l >> 4;
    const int li = l & 15;

    short8 bfr[12][2];
    float bn[12];
#pragma unroll
    for (int nt = 0; nt < 12; ++nt) {
        bn[nt] = bias[nt * 16 + li];
#pragma unroll
        for (int c = 0; c < 2; ++c) {
#pragma unroll
            for (int j = 0; j < 8; ++j) {
                int k = c * 32 + lg * 8 + j;
                bfr[nt][c][j] = (short)f2bf(W[k * 192 + nt * 16 + li]);
            }
        }
    }

    for (int tile = blockIdx.x * 4 + wv; tile < Mtiles; tile += tilestride) {
        long row = (long)tile * 16 + li;
        {
            int bb = (int)(row / TT);
            int tt = (int)(row - (long)bb * TT);
            int vld = (tt < hist_len[bb]) ? 1 : 0;
            if (__ballot(vld) == 0ull) continue;
        }

        short8 a[2];
        if (GATHER) {
            long id = idx[row];
            const float* tp = tablef + id * 64 + lg * 8;
#pragma unroll
            for (int c = 0; c < 2; ++c) {
                f32x4 v0 = *(const f32x4*)(tp + c * 32);
                f32x4 v1 = *(const f32x4*)(tp + c * 32 + 4);
#pragma unroll
                for (int j = 0; j < 4; ++j) {
                    a[c][j] = (short)f2bf(v0[j]);
                    a[c][4 + j] = (short)f2bf(v1[j]);
                }
            }
        } else {
#pragma unroll
            for (int c = 0; c < 2; ++c)
                a[c] = *(const short8*)(Abf + row * 64 + c * 32 + lg * 8);
        }

        f32x4 acc[12];
#pragma unroll
        for (int nt = 0; nt < 12; ++nt) acc[nt] = (f32x4){0.f, 0.f, 0.f, 0.f};
#pragma unroll
        for (int c = 0; c < 2; ++c)
#pragma unroll
            for (int nt = 0; nt < 12; ++nt)
                acc[nt] = __builtin_amdgcn_mfma_f32_16x16x32_bf16(a[c], bfr[nt][c], acc[nt], 0, 0, 0);

#pragma unroll
        for (int nt = 0; nt < 12; ++nt)
#pragma unroll
            for (int j = 0; j < 4; ++j) {
                long orow = (long)tile * 16 + lg * 4 + j;
                out[orow * 192 + nt * 16 + li] = f2bf(acc[nt][j] + bn[nt]);
            }
    }
}

// ---------------------------------------------------------------------------
// k_scan10: recurrent h@U, ONE WAVE per batch row, zero barriers.
// U lives in LDS (24 KB bf16 pairs, staged once) and is RE-READ each step:
// this embraces the compiler's refusal to keep weights register-resident
// (r3-r10) by making the per-step reload a dense pipelined LDS stream
// instead of serialized L1/L2 latency chains.
// Row l = lane l's gate column, 96 uints [z(32)|r(32)|h(32)].
// XOR swizzle (idx^=(l&7)<<2, 16B granularity, write AND read) makes the
// stride-384B rows conflict-free; uint4 reads still deliver pairs 4q..4q+3
// in order (XOR preserves low 2 bits).
// ---------------------------------------------------------------------------
template <int AUG>
__global__ __launch_bounds__(64, 1) void k_scan10(
    const unsigned short* __restrict__ xw,   // (B*T,192) bf16
    const float* __restrict__ U,             // (64,192)
    const int* __restrict__ hist_len,
    const float* __restrict__ scores,        // (B,T)
    unsigned short* __restrict__ hout,       // (B,T,64) bf16 (GRU1)
    float* __restrict__ hfinal)              // (B,64) f32 (AUGRU)
{
    __shared__ unsigned Ul[64 * 96];         // 24 KB bf16-pair weight image
    __shared__ unsigned hb[32];              // 64 bf16 h values as 32 pairs
    const int l = threadIdx.x;
    const int b = blockIdx.x;
    const int len = hist_len[b];
    const unsigned sw = ((unsigned)l & 7u) << 2;  // uint-index XOR (16B chunks)

    unsigned* rowp = Ul + l * 96;
    // stage this lane's gate-column of U as bf16 pairs (one-time)
    for (int kk = 0; kk < 32; ++kk) {
        unsigned pz = cvt_pk_bf16(U[(2 * kk) * 192 + l],       U[(2 * kk + 1) * 192 + l]);
        unsigned pr = cvt_pk_bf16(U[(2 * kk) * 192 + 64 + l],  U[(2 * kk + 1) * 192 + 64 + l]);
        unsigned ph = cvt_pk_bf16(U[(2 * kk) * 192 + 128 + l], U[(2 * kk + 1) * 192 + 128 + l]);
        rowp[(kk ^ sw)]      = pz;
        rowp[32 + (kk ^ sw)] = pr;
        rowp[64 + (kk ^ sw)] = ph;
    }

    const unsigned short* xwr = xw + (size_t)b * TT * 192;
    const float* scr = scores + (size_t)b * TT;
    unsigned short* hor = hout + (size_t)b * TT * 64;

    unsigned short* hbs = (unsigned short*)hb;
    float h = 0.f;
    hbs[l] = 0;   // bf16 zero

    // one-step-ahead prefetch of xw row (+ score)
    unsigned short nz = xwr[l], nr = xwr[64 + l], nh = xwr[128 + l];
    float ns = AUG ? scr[0] : 0.f;

    const uint4* H4 = (const uint4*)hb;

    for (int t = 0; t < len; ++t) {
        const unsigned short cz = nz, cr = nr, ch = nh;
        const float cs = ns;
        if (t + 1 < len) {
            const unsigned short* p = xwr + (size_t)(t + 1) * 192;
            nz = p[l]; nr = p[64 + l]; nh = p[128 + l];
            if (AUG) ns = scr[t + 1];
        }

        // 8 uniform h reads (broadcast) + 24 swizzled U reads + 96 dot2
        float az0 = 0.f, az1 = 0.f, ar0 = 0.f, ar1 = 0.f, ah0 = 0.f, ah1 = 0.f;
#pragma unroll
        for (int q = 0; q < 8; ++q) {
            uint4 hq = H4[q];
            uint4 uz = *(const uint4*)(rowp + ((4 * q) ^ sw));
            uint4 ur = *(const uint4*)(rowp + 32 + ((4 * q) ^ sw));
            uint4 uh = *(const uint4*)(rowp + 64 + ((4 * q) ^ sw));
            az0 = dot2bf(hq.x, uz.x, az0);
            ar0 = dot2bf(hq.x, ur.x, ar0);
            ah0 = dot2bf(hq.x, uh.x, ah0);
            az1 = dot2bf(hq.y, uz.y, az1);
            ar1 = dot2bf(hq.y, ur.y, ar1);
            ah1 = dot2bf(hq.y, uh.y, ah1);
            az0 = dot2bf(hq.z, uz.z, az0);
            ar0 = dot2bf(hq.z, ur.z, ar0);
            ah0 = dot2bf(hq.z, uh.z, ah0);
            az1 = dot2bf(hq.w, uz.w, az1);
            ar1 = dot2bf(hq.w, ur.w, ar1);
            ah1 = dot2bf(hq.w, uh.w, ah1);
        }
        float azf = az0 + az1, arf = ar0 + ar1, ahf = ah0 + ah1;

        float zg = sigmoidf_(bf2f(cz) + azf);
        if (AUG) zg *= cs;
        float rg = sigmoidf_(bf2f(cr) + arf);
        float hv = tanh_fast(bf2f(ch) + rg * ahf);
        h = (1.f - zg) * h + zg * hv;

        const unsigned short hbf = f2bf(h);
        hbs[l] = hbf;  // may-alias this step's h reads -> ordered; in-order DS pipe
        if (!AUG) hor[(size_t)t * 64 + l] = hbf;
    }

    if (AUG) {
        hfinal[(size_t)b * 64 + l] = h;
    } else {
        const unsigned short fro = f2bf(h);
        for (int t = len; t < TT; ++t) hor[(size_t)t * 64 + l] = fro;
    }
}

// ---------------------------------------------------------------------------
// k_att: bf16 MFMA attention + fused softmax, len-clipped tiles (unchanged)
// ---------------------------------------------------------------------------
__global__ __launch_bounds__(256, 2) void k_att(
    const float* __restrict__ target, const unsigned short* __restrict__ seq_hb,
    const float* __restrict__ W1, const float* __restrict__ b1,
    const float* __restrict__ W2, const float* __restrict__ b2,
    const float* __restrict__ W3, const float* __restrict__ b3,
    const int* __restrict__ hist_len, float* __restrict__ scores)
{
    __shared__ unsigned short W1f[8 * 4 * 64 * 8];  // frag layout, 32 KB
    __shared__ float a1s[4][16][68];
    __shared__ float logit_lds[208];
    __shared__ float red[8];

    const int tid = threadIdx.x;
    const int wv = tid >> 6, l = tid & 63;
    const int lg = l >> 4, li = l & 15;
    const int b = blockIdx.x;
    const int len = hist_len[b];

    if (tid < 208) logit_lds[tid] = -1e9f;
    for (int i = tid; i < 8 * 4 * 64 * 8; i += 256) {
        int j = i & 7, ll = (i >> 3) & 63, nt = (i >> 9) & 3, c = i >> 11;
        int k = c * 32 + (ll >> 4) * 8 + j;
        int col = nt * 16 + (ll & 15);
        W1f[i] = f2bf(W1[k * 64 + col]);
    }
    __syncthreads();

    short8 w1r[8][4];
    const short8* wf = (const short8*)W1f;
#pragma unroll
    for (int c = 0; c < 8; ++c)
#pragma unroll
        for (int nt = 0; nt < 4; ++nt)
            w1r[c][nt] = wf[(c * 4 + nt) * 64 + l];

    short8 w2r[2];
#pragma unroll
    for (int c = 0; c < 2; ++c) {
        U8 t8;
#pragma unroll
        for (int m = 0; m < 4; ++m) {
            int k0 = c * 32 + lg * 8 + 2 * m;
            t8.u[m] = cvt_pk_bf16(W2[k0 * 16 + li], W2[(k0 + 1) * 16 + li]);
        }
        w2r[c] = t8.s8;
    }

    float b1v[4];
#pragma unroll
    for (int nt = 0; nt < 4; ++nt) b1v[nt] = b1[nt * 16 + li];
    const float b2v = b2[li];
    const float w3v = W3[li];
    const float b3r = b3[0];

    const float* qp = target + (size_t)b * 64;
    float qf_lo[8], qf_hi[8];
#pragma unroll
    for (int j = 0; j < 8; ++j) { qf_lo[j] = qp[lg * 8 + j]; qf_hi[j] = qp[32 + lg * 8 + j]; }
    U8 q8l, q8h;
#pragma unroll
    for (int m = 0; m < 4; ++m) {
        q8l.u[m] = cvt_pk_bf16(qf_lo[2 * m], qf_lo[2 * m + 1]);
        q8h.u[m] = cvt_pk_bf16(qf_hi[2 * m], qf_hi[2 * m + 1]);
    }

    for (int mt = wv; mt * 16 < len; mt += 4) {
        const int t = mt * 16 + li;
        const int tld = (t < TT) ? t : TT - 1;
        const unsigned short* hp = seq_hb + ((size_t)b * TT + tld) * 64 + lg * 8;
        short8 h8l = *(const short8*)hp;
        short8 h8h = *(const short8*)(hp + 32);

        U8 d8l, d8h, m8l, m8h;
#pragma unroll
        for (int m = 0; m < 4; ++m) {
            float h0, h1, d0, d1, p0, p1;
            h0 = bf2f((unsigned short)h8l[2 * m]); h1 = bf2f((unsigned short)h8l[2 * m + 1]);
            d0 = qf_lo[2 * m] - h0; d1 = qf_lo[2 * m + 1] - h1;
            p0 = qf_lo[2 * m] * h0; p1 = qf_lo[2 * m + 1] * h1;
            d8l.u[m] = cvt_pk_bf16(d0, d1);
            m8l.u[m] = cvt_pk_bf16(p0, p1);
            h0 = bf2f((unsigned short)h8h[2 * m]); h1 = bf2f((unsigned short)h8h[2 * m + 1]);
            d0 = qf_hi[2 * m] - h0; d1 = qf_hi[2 * m + 1] - h1;
            p0 = qf_hi[2 * m] * h0; p1 = qf_hi[2 * m + 1] * h1;
            d8h.u[m] = cvt_pk_bf16(d0, d1);
            m8h.u[m] = cvt_pk_bf16(p0, p1);
        }

        f32x4 acc[4];
#pragma unroll
        for (int nt = 0; nt < 4; ++nt) acc[nt] = (f32x4){0.f, 0.f, 0.f, 0.f};
#pragma unroll
        for (int nt = 0; nt < 4; ++nt) {
            acc[nt] = __builtin_amdgcn_mfma_f32_16x16x32_bf16(q8l.s8, w1r[0][nt], acc[nt], 0, 0, 0);
            acc[nt] = __builtin_amdgcn_mfma_f32_16x16x32_bf16(q8h.s8, w1r[1][nt], acc[nt], 0, 0, 0);
            acc[nt] = __builtin_amdgcn_mfma_f32_16x16x32_bf16(h8l,    w1r[2][nt], acc[nt], 0, 0, 0);
            acc[nt] = __builtin_amdgcn_mfma_f32_16x16x32_bf16(h8h,    w1r[3][nt], acc[nt], 0, 0, 0);
            acc[nt] = __builtin_amdgcn_mfma_f32_16x16x32_bf16(d8l.s8, w1r[4][nt], acc[nt], 0, 0, 0);
            acc[nt] = __builtin_amdgcn_mfma_f32_16x16x32_bf16(d8h.s8, w1r[5][nt], acc[nt], 0, 0, 0);
            acc[nt] = __builtin_amdgcn_mfma_f32_16x16x32_bf16(m8l.s8, w1r[6][nt], acc[nt], 0, 0, 0);
            acc[nt] = __builtin_amdgcn_mfma_f32_16x16x32_bf16(m8h.s8, w1r[7][nt], acc[nt], 0, 0, 0);
        }

#pragma unroll
        for (int nt = 0; nt < 4; ++nt)
#pragma unroll
            for (int jj = 0; jj < 4; ++jj) {
                float v = acc[nt][jj] + b1v[nt];
                a1s[wv][lg * 4 + jj][nt * 16 + li] = (v > 0.f) ? v : 0.25f * v;
            }

        const float* arow = &a1s[wv][li][0];
        f32x4 acc2 = (f32x4){0.f, 0.f, 0.f, 0.f};
#pragma unroll
        for (int c2 = 0; c2 < 2; ++c2) {
            f32x4 v0 = *(const f32x4*)(arow + c2 * 32 + lg * 8);
            f32x4 v1 = *(const f32x4*)(arow + c2 * 32 + lg * 8 + 4);
            U8 a2f;
            a2f.u[0] = cvt_pk_bf16(v0[0], v0[1]);
            a2f.u[1] = cvt_pk_bf16(v0[2], v0[3]);
            a2f.u[2] = cvt_pk_bf16(v1[0], v1[1]);
            a2f.u[3] = cvt_pk_bf16(v1[2], v1[3]);
            acc2 = __builtin_amdgcn_mfma_f32_16x16x32_bf16(a2f.s8, w2r[c2], acc2, 0, 0, 0);
        }

#pragma unroll
        for (int jj = 0; jj < 4; ++jj) {
            float a2 = acc2[jj] + b2v;
            a2 = (a2 > 0.f) ? a2 : 0.25f * a2;
            float part = a2 * w3v;
            part += __shfl_xor(part, 1);
            part += __shfl_xor(part, 2);
            part += __shfl_xor(part, 4);
            part += __shfl_xor(part, 8);
            int tt = mt * 16 + lg * 4 + jj;
            if (li == 0 && tt < TT)
                logit_lds[tt] = (tt < len) ? (part + b3r) : -1e9f;
        }
    }
    __syncthreads();

    float v = (tid < TT) ? logit_lds[tid] : -1e30f;
    float m = v;
#pragma unroll
    for (int s = 1; s < 64; s <<= 1) m = fmaxf(m, __shfl_xor(m, s));
    if (l == 0) red[wv] = m;
    __syncthreads();
    m = fmaxf(fmaxf(red[0], red[1]), fmaxf(red[2], red[3]));
    float e = (tid < TT) ? __expf(v - m) : 0.f;
    float sum = e;
#pragma unroll
    for (int s = 1; s < 64; s <<= 1) sum += __shfl_xor(sum, s);
    if (l == 0) red[4 + wv] = sum;
    __syncthreads();
    float inv = __fdividef(1.f, red[4] + red[5] + red[6] + red[7]);
    if (tid < TT) scores[(size_t)b * TT + tid] = e * inv;
}

// ---------------------------------------------------------------------------
// FFN chain (tiny, unchanged)
// ---------------------------------------------------------------------------
__global__ __launch_bounds__(256) void k_fc1(const float* __restrict__ fin,
                                             const float* __restrict__ tgt,
                                             const float* __restrict__ oth,
                                             const float* __restrict__ Wt,
                                             const float* __restrict__ bvec,
                                             float* __restrict__ fout) {
    __shared__ float z0[164];
    int b = blockIdx.x, tid = threadIdx.x;
    if (tid < 64) z0[tid] = fin[b * 64 + tid];
    else if (tid < 128) z0[tid] = tgt[b * 64 + tid - 64];
    else if (tid < 164) z0[tid] = oth[b * 36 + tid - 128];
    __syncthreads();
    float acc = bvec[tid];
#pragma unroll 4
    for (int k = 0; k < 164; ++k) acc += z0[k] * Wt[k * 256 + tid];
    fout[(size_t)b * 256 + tid] = acc;
}

template <int F>
__global__ __launch_bounds__(256) void k_stats(const float* __restrict__ x, float* __restrict__ stat) {
    int c = blockIdx.x, tid = threadIdx.x;
    float s = 0.f, sq = 0.f;
    for (int i = tid; i < BB; i += 256) {
        float v = x[(size_t)i * F + c];
        s += v; sq += v * v;
    }
#pragma unroll
    for (int m = 1; m < 64; m <<= 1) { s += __shfl_xor(s, m); sq += __shfl_xor(sq, m); }
    __shared__ float rs[4], rq[4];
    if ((tid & 63) == 0) { rs[tid >> 6] = s; rq[tid >> 6] = sq; }
    __syncthreads();
    if (tid == 0) {
        float S = rs[0] + rs[1] + rs[2] + rs[3];
        float Q = rq[0] + rq[1] + rq[2] + rq[3];
        float mean = S * (1.f / BB);
        float var = Q * (1.f / BB) - mean * mean;
        stat[c] = mean;
        stat[F + c] = var;
    }
}

__global__ __launch_bounds__(256) void k_fc2(const float* __restrict__ f1,
                                             const float* __restrict__ st1,
                                             const float* __restrict__ Wt,
                                             const float* __restrict__ bvec,
                                             float* __restrict__ f2) {
    __shared__ float z[256];
    int b = blockIdx.x, tid = threadIdx.x;
    float x = f1[(size_t)b * 256 + tid];
    z[tid] = dicef_(x, st1[tid], st1[256 + tid]);
    __syncthreads();
    if (tid < 128) {
        float acc = bvec[tid];
#pragma unroll 4
        for (int k = 0; k < 256; ++k) acc += z[k] * Wt[k * 128 + tid];
        f2[(size_t)b * 128 + tid] = acc;
    }
}

__global__ __launch_bounds__(128) void k_fc3(const float* __restrict__ f2,
                                             const float* __restrict__ st2,
                                             const float* __restrict__ Wt,
                                             const float* __restrict__ bvec,
                                             float* __restrict__ f3) {
    __shared__ float z[128];
    int b = blockIdx.x, tid = threadIdx.x;
    float x = f2[(size_t)b * 128 + tid];
    z[tid] = dicef_(x, st2[tid], st2[128 + tid]);
    __syncthreads();
    if (tid < 64) {
        float acc = bvec[tid];
#pragma unroll 4
        for (int k = 0; k < 128; ++k) acc += z[k] * Wt[k * 64 + tid];
        f3[(size_t)b * 64 + tid] = acc;
    }
}

__global__ void k_out(const float* __restrict__ f3, const float* __restrict__ st3,
                      const float* __restrict__ outW, const float* __restrict__ outb,
                      float* __restrict__ out) {
    int b = blockIdx.x, l = threadIdx.x;  // 64 threads
    float x = f3[(size_t)b * 64 + l];
    float z = dicef_(x, st3[l], st3[64 + l]);
    float p = z * outW[l];
#pragma unroll
    for (int m = 1; m < 64; m <<= 1) p += __shfl_xor(p, m);
    if (l == 0) out[b] = sigmoidf_(p + outb[0]);
}

// ---------------------------------------------------------------------------
extern "C" void kernel_launch(void* const* d_in, const int* in_sizes, int n_in,
                              void* d_out, int out_size, void* d_ws, size_t ws_size,
                              hipStream_t stream) {
    const float* dense      = (const float*)d_in[0];
    const int*   sparse     = (const int*)d_in[1];
    const int*   seq_idx    = (const int*)d_in[2];
    const int*   item_idx   = (const int*)d_in[3];
    const int*   hist_len   = (const int*)d_in[4];
    const float* item_table = (const float*)d_in[5];
    const float* other_tab  = (const float*)d_in[6];
    const float* gru_W = (const float*)d_in[7];
    const float* gru_U = (const float*)d_in[8];
    const float* gru_b = (const float*)d_in[9];
    const float* aug_W = (const float*)d_in[10];
    const float* aug_U = (const float*)d_in[11];
    const float* aug_b = (const float*)d_in[12];
    const float* att_W1 = (const float*)d_in[13];
    const float* att_b1 = (const float*)d_in[14];
    const float* att_W2 = (const float*)d_in[15];
    const float* att_b2 = (const float*)d_in[16];
    const float* att_W3 = (const float*)d_in[17];
    const float* att_b3 = (const float*)d_in[18];
    const float* ffn_W1 = (const float*)d_in[19];
    const float* ffn_b1 = (const float*)d_in[20];
    const float* ffn_W2 = (const float*)d_in[21];
    const float* ffn_b2 = (const float*)d_in[22];
    const float* ffn_W3 = (const float*)d_in[23];
    const float* ffn_b3 = (const float*)d_in[24];
    const float* out_W  = (const float*)d_in[25];
    const float* out_b  = (const float*)d_in[26];

    float* wsf = (float*)d_ws;
    unsigned short* xwb   = (unsigned short*)(wsf);              // (B*T,192) bf16
    unsigned short* seqhb = (unsigned short*)(wsf + 19660800);   // (B,T,64) bf16
    float* scores = wsf + 26214400;            // B*T
    float* target = wsf + 26419200;            // B*64
    float* other  = wsf + 26484736;            // B*36
    float* finals = wsf + 26521600;            // B*64
    float* f1     = wsf + 26587136;            // B*256
    float* f2     = wsf + 26849280;            // B*128
    float* f3     = wsf + 26980352;            // B*64
    float* st1    = wsf + 27045888;            // 512
    float* st2    = wsf + 27046400;            // 256
    float* st3    = wsf + 27046656;            // 128

    float* dout = (float*)d_out;
    const int Mtiles = (BB * TT) / 16;  // 12800

    k_prep<<<BB, 64, 0, stream>>>(dense, sparse, item_idx, item_table, other_tab, target, other);

    // xw1 = gather(item_table, seq_idx) @ gru_W + gru_b  (bf16 MFMA, masked tiles skipped)
    k_xw<1><<<800, 256, 0, stream>>>(seq_idx, item_table, nullptr, gru_W, gru_b, hist_len, xwb, Mtiles, 3200);

    // GRU1 recurrence -> seq_h bf16 (B,T,64)   [1 wave/row, U re-read from LDS]
    k_scan10<0><<<BB, 64, 0, stream>>>(xwb, gru_U, hist_len, scores, seqhb, finals);

    // attention MLP (MFMA) + fused softmax -> scores
    k_att<<<BB, 256, 0, stream>>>(target, seqhb, att_W1, att_b1, att_W2, att_b2,
                                  att_W3, att_b3, hist_len, scores);

    // xw2 = seq_h @ aug_W + aug_b  (bf16 MFMA, masked tiles skipped)
    k_xw<0><<<800, 256, 0, stream>>>(nullptr, nullptr, seqhb, aug_W, aug_b, hist_len, xwb, Mtiles, 3200);

    // AUGRU recurrence -> finals f32 (B,64)
    k_scan10<1><<<BB, 64, 0, stream>>>(xwb, aug_U, hist_len, scores, seqhb, finals);

    k_fc1<<<BB, 256, 0, stream>>>(finals, target, other, ffn_W1, ffn_b1, f1);
    k_stats<256><<<256, 256, 0, stream>>>(f1, st1);
    k_fc2<<<BB, 256, 0, stream>>>(f1, st1, ffn_W2, ffn_b2, f2);
    k_stats<128><<<128, 256, 0, stream>>>(f2, st2);
    k_fc3<<<BB, 128, 0, stream>>>(f2, st2, ffn_W3, ffn_b3, f3);
    k_stats<64><<<64, 256, 0, stream>>>(f3, st3);
    k_out<<<BB, 64, 0, stream>>>(f3, st3, out_W, out_b, dout);
}

// Round 12
// 403.914 us; speedup vs baseline: 1.2109x; 1.0070x over previous
//
#include <hip/hip_runtime.h>

#define BB 1024
#define TT 200

typedef __attribute__((ext_vector_type(8))) short short8;
typedef __attribute__((ext_vector_type(2))) short short2v;
typedef __attribute__((ext_vector_type(4))) float f32x4;

__device__ __forceinline__ float sigmoidf_(float x) { return __fdividef(1.0f, 1.0f + __expf(-x)); }
__device__ __forceinline__ float tanh_fast(float x) {
    x = fminf(15.f, fmaxf(-15.f, x));
    float e = __expf(-2.f * x);
    return __fdividef(1.f - e, 1.f + e);
}
__device__ __forceinline__ float dicef_(float x, float m, float v) {
    return x * sigmoidf_((x - m) * rsqrtf(v + 1e-9f));
}
__device__ __forceinline__ unsigned short f2bf(float f) {
    unsigned u = __float_as_uint(f);
    unsigned r = u + 0x7fffu + ((u >> 16) & 1u);
    return (unsigned short)(r >> 16);
}
__device__ __forceinline__ float bf2f(unsigned short h) {
    return __uint_as_float(((unsigned)h) << 16);
}
__device__ __forceinline__ unsigned cvt_pk_bf16(float lo, float hi) {
    unsigned r;
    asm("v_cvt_pk_bf16_f32 %0, %1, %2" : "=v"(r) : "v"(lo), "v"(hi));
    return r;
}
union U8 { short8 s8; unsigned u[4]; };

// dot of two bf16 pairs accumulating into f32
#if __has_builtin(__builtin_amdgcn_fdot2_f32_bf16)
__device__ __forceinline__ float dot2bf(unsigned h2, unsigned u2, float c) {
    union { unsigned u; short2v s; } A, B;
    A.u = h2; B.u = u2;
    return __builtin_amdgcn_fdot2_f32_bf16(A.s, B.s, c, false);
}
#else
__device__ __forceinline__ float dot2bf(unsigned h2, unsigned u2, float c) {
    float h0 = __uint_as_float(h2 << 16), h1 = __uint_as_float(h2 & 0xffff0000u);
    float u0 = __uint_as_float(u2 << 16), u1 = __uint_as_float(u2 & 0xffff0000u);
    return fmaf(h1, u1, fmaf(h0, u0, c));
}
#endif

// ---------------------------------------------------------------------------
// k_prep
// ---------------------------------------------------------------------------
__global__ void k_prep(const float* __restrict__ dense, const int* __restrict__ sparse,
                       const int* __restrict__ item_idx, const float* __restrict__ table,
                       const float* __restrict__ other_tables,
                       float* __restrict__ target, float* __restrict__ other) {
    int b = blockIdx.x, l = threadIdx.x;  // 64 threads
    target[b * 64 + l] = table[(size_t)item_idx[b] * 64 + l];
    if (l < 4) other[b * 36 + l] = dense[b * 4 + l];
    else if (l < 20) other[b * 36 + l] = other_tables[(size_t)sparse[b * 2 + 0] * 16 + (l - 4)];
    else if (l < 36) other[b * 36 + l] = other_tables[1000 * 16 + (size_t)sparse[b * 2 + 1] * 16 + (l - 20)];
}

// ---------------------------------------------------------------------------
// k_xw: XW = X @ W + bias, bf16 MFMA, masked-tile skip (unchanged)
// ---------------------------------------------------------------------------
template <int GATHER>
__global__ __launch_bounds__(256, 1) void k_xw(
    const int* __restrict__ idx, const float* __restrict__ tablef,
    const unsigned short* __restrict__ Abf,
    const float* __restrict__ W, const float* __restrict__ bias,
    const int* __restrict__ hist_len,
    unsigned short* __restrict__ out, int Mtiles, int tilestride)
{
    const int l = threadIdx.x & 63;
    const int wv = threadIdx.x >> 6;
    const int lg = l >> 4;
    const int li = l & 15;

    short8 bfr[12][2];
    float bn[12];
#pragma unroll
    for (int nt = 0; nt < 12; ++nt) {
        bn[nt] = bias[nt * 16 + li];
#pragma unroll
        for (int c = 0; c < 2; ++c) {
#pragma unroll
            for (int j = 0; j < 8; ++j) {
                int k = c * 32 + lg * 8 + j;
                bfr[nt][c][j] = (short)f2bf(W[k * 192 + nt * 16 + li]);
            }
        }
    }

    for (int tile = blockIdx.x * 4 + wv; tile < Mtiles; tile += tilestride) {
        long row = (long)tile * 16 + li;
        {
            int bb = (int)(row / TT);
            int tt = (int)(row - (long)bb * TT);
            int vld = (tt < hist_len[bb]) ? 1 : 0;
            if (__ballot(vld) == 0ull) continue;
        }

        short8 a[2];
        if (GATHER) {
            long id = idx[row];
            const float* tp = tablef + id * 64 + lg * 8;
#pragma unroll
            for (int c = 0; c < 2; ++c) {
                f32x4 v0 = *(const f32x4*)(tp + c * 32);
                f32x4 v1 = *(const f32x4*)(tp + c * 32 + 4);
#pragma unroll
                for (int j = 0; j < 4; ++j) {
                    a[c][j] = (short)f2bf(v0[j]);
                    a[c][4 + j] = (short)f2bf(v1[j]);
                }
            }
        } else {
#pragma unroll
            for (int c = 0; c < 2; ++c)
                a[c] = *(const short8*)(Abf + row * 64 + c * 32 + lg * 8);
        }

        f32x4 acc[12];
#pragma unroll
        for (int nt = 0; nt < 12; ++nt) acc[nt] = (f32x4){0.f, 0.f, 0.f, 0.f};
#pragma unroll
        for (int c = 0; c < 2; ++c)
#pragma unroll
            for (int nt = 0; nt < 12; ++nt)
                acc[nt] = __builtin_amdgcn_mfma_f32_16x16x32_bf16(a[c], bfr[nt][c], acc[nt], 0, 0, 0);

#pragma unroll
        for (int nt = 0; nt < 12; ++nt)
#pragma unroll
            for (int j = 0; j < 4; ++j) {
                long orow = (long)tile * 16 + lg * 4 + j;
                out[orow * 192 + nt * 16 + li] = f2bf(acc[nt][j] + bn[nt]);
            }
    }
}

// ---------------------------------------------------------------------------
// k_scan11: recurrent h@U, ONE WAVE per batch row, zero barriers.
// U re-read from LDS each step (r11 structure, proven) + DEPTH-4 software-
// pipelined xw prefetch: slot i feeds step t with t%4==i and is reloaded
// for t+4 during step t (~1200cy coverage vs ~900cy L3/HBM latency).
// Slots are NAMED registers; main loop statically unrolled 4x; tail uses
// static slot references (no dynamic indexing -> no scratch).
// ---------------------------------------------------------------------------
template <int AUG>
__global__ __launch_bounds__(64, 1) void k_scan11(
    const unsigned short* __restrict__ xw,   // (B*T,192) bf16
    const float* __restrict__ U,             // (64,192)
    const int* __restrict__ hist_len,
    const float* __restrict__ scores,        // (B,T)
    unsigned short* __restrict__ hout,       // (B,T,64) bf16 (GRU1)
    float* __restrict__ hfinal)              // (B,64) f32 (AUGRU)
{
    __shared__ unsigned Ul[64 * 96];         // 24 KB bf16-pair weight image
    __shared__ unsigned hb[32];              // 64 bf16 h values as 32 pairs
    const int l = threadIdx.x;
    const int b = blockIdx.x;
    const int len = hist_len[b];
    const unsigned sw = ((unsigned)l & 7u) << 2;  // uint-index XOR (16B chunks)

    unsigned* rowp = Ul + l * 96;
    for (int kk = 0; kk < 32; ++kk) {
        unsigned pz = cvt_pk_bf16(U[(2 * kk) * 192 + l],       U[(2 * kk + 1) * 192 + l]);
        unsigned pr = cvt_pk_bf16(U[(2 * kk) * 192 + 64 + l],  U[(2 * kk + 1) * 192 + 64 + l]);
        unsigned ph = cvt_pk_bf16(U[(2 * kk) * 192 + 128 + l], U[(2 * kk + 1) * 192 + 128 + l]);
        rowp[(kk ^ sw)]      = pz;
        rowp[32 + (kk ^ sw)] = pr;
        rowp[64 + (kk ^ sw)] = ph;
    }

    const unsigned short* xwr = xw + (size_t)b * TT * 192;
    const float* scr = scores + (size_t)b * TT;
    unsigned short* hor = hout + (size_t)b * TT * 64;

    unsigned short* hbs = (unsigned short*)hb;
    float h = 0.f;
    hbs[l] = 0;   // bf16 zero

    const uint4* H4 = (const uint4*)hb;

    // one GRU/AUGRU step consuming prefetched xw slot values
    auto step = [&](unsigned short cz, unsigned short cr, unsigned short ch,
                    float cs, int t) {
        float az0 = 0.f, az1 = 0.f, ar0 = 0.f, ar1 = 0.f, ah0 = 0.f, ah1 = 0.f;
#pragma unroll
        for (int q = 0; q < 8; ++q) {
            uint4 hq = H4[q];
            uint4 uz = *(const uint4*)(rowp + ((4 * q) ^ sw));
            uint4 ur = *(const uint4*)(rowp + 32 + ((4 * q) ^ sw));
            uint4 uh = *(const uint4*)(rowp + 64 + ((4 * q) ^ sw));
            az0 = dot2bf(hq.x, uz.x, az0);
            ar0 = dot2bf(hq.x, ur.x, ar0);
            ah0 = dot2bf(hq.x, uh.x, ah0);
            az1 = dot2bf(hq.y, uz.y, az1);
            ar1 = dot2bf(hq.y, ur.y, ar1);
            ah1 = dot2bf(hq.y, uh.y, ah1);
            az0 = dot2bf(hq.z, uz.z, az0);
            ar0 = dot2bf(hq.z, ur.z, ar0);
            ah0 = dot2bf(hq.z, uh.z, ah0);
            az1 = dot2bf(hq.w, uz.w, az1);
            ar1 = dot2bf(hq.w, ur.w, ar1);
            ah1 = dot2bf(hq.w, uh.w, ah1);
        }
        float azf = az0 + az1, arf = ar0 + ar1, ahf = ah0 + ah1;

        float zg = sigmoidf_(bf2f(cz) + azf);
        if (AUG) zg *= cs;
        float rg = sigmoidf_(bf2f(cr) + arf);
        float hv = tanh_fast(bf2f(ch) + rg * ahf);
        h = (1.f - zg) * h + zg * hv;

        const unsigned short hbf = f2bf(h);
        hbs[l] = hbf;  // may-alias this step's h reads -> ordered; in-order DS pipe
        if (!AUG) hor[(size_t)t * 64 + l] = hbf;
    };

#define DECL_SLOT(i) unsigned short pz##i = 0, pr##i = 0, ph##i = 0; float ps##i = 0.f;
#define LOAD_SLOT(i, tt) { const unsigned short* p_ = xwr + (size_t)(tt) * 192; \
        pz##i = p_[l]; pr##i = p_[64 + l]; ph##i = p_[128 + l]; \
        if (AUG) ps##i = scr[(tt)]; }

    DECL_SLOT(0) DECL_SLOT(1) DECL_SLOT(2) DECL_SLOT(3)
    if (len > 0) LOAD_SLOT(0, 0)
    if (len > 1) LOAD_SLOT(1, 1)
    if (len > 2) LOAD_SLOT(2, 2)
    if (len > 3) LOAD_SLOT(3, 3)

    const int lenm = len & ~3;
    int t = 0;
    for (; t < lenm; t += 4) {
        {
            const unsigned short cz = pz0, cr = pr0, ch = ph0; const float cs = ps0;
            if (t + 4 < len) LOAD_SLOT(0, t + 4)
            step(cz, cr, ch, cs, t);
        }
        {
            const unsigned short cz = pz1, cr = pr1, ch = ph1; const float cs = ps1;
            if (t + 5 < len) LOAD_SLOT(1, t + 5)
            step(cz, cr, ch, cs, t + 1);
        }
        {
            const unsigned short cz = pz2, cr = pr2, ch = ph2; const float cs = ps2;
            if (t + 6 < len) LOAD_SLOT(2, t + 6)
            step(cz, cr, ch, cs, t + 2);
        }
        {
            const unsigned short cz = pz3, cr = pr3, ch = ph3; const float cs = ps3;
            if (t + 7 < len) LOAD_SLOT(3, t + 7)
            step(cz, cr, ch, cs, t + 3);
        }
    }
    // tail: 0..3 steps, slots 0..2 already loaded (lenm % 4 == 0)
    if (t + 0 < len) step(pz0, pr0, ph0, ps0, t + 0);
    if (t + 1 < len) step(pz1, pr1, ph1, ps1, t + 1);
    if (t + 2 < len) step(pz2, pr2, ph2, ps2, t + 2);

#undef DECL_SLOT
#undef LOAD_SLOT

    if (AUG) {
        hfinal[(size_t)b * 64 + l] = h;
    } else {
        const unsigned short fro = f2bf(h);
        for (int tt = len; tt < TT; ++tt) hor[(size_t)tt * 64 + l] = fro;
    }
}

// ---------------------------------------------------------------------------
// k_att: bf16 MFMA attention + fused softmax, len-clipped tiles (unchanged)
// ---------------------------------------------------------------------------
__global__ __launch_bounds__(256, 2) void k_att(
    const float* __restrict__ target, const unsigned short* __restrict__ seq_hb,
    const float* __restrict__ W1, const float* __restrict__ b1,
    const float* __restrict__ W2, const float* __restrict__ b2,
    const float* __restrict__ W3, const float* __restrict__ b3,
    const int* __restrict__ hist_len, float* __restrict__ scores)
{
    __shared__ unsigned short W1f[8 * 4 * 64 * 8];  // frag layout, 32 KB
    __shared__ float a1s[4][16][68];
    __shared__ float logit_lds[208];
    __shared__ float red[8];

    const int tid = threadIdx.x;
    const int wv = tid >> 6, l = tid & 63;
    const int lg = l >> 4, li = l & 15;
    const int b = blockIdx.x;
    const int len = hist_len[b];

    if (tid < 208) logit_lds[tid] = -1e9f;
    for (int i = tid; i < 8 * 4 * 64 * 8; i += 256) {
        int j = i & 7, ll = (i >> 3) & 63, nt = (i >> 9) & 3, c = i >> 11;
        int k = c * 32 + (ll >> 4) * 8 + j;
        int col = nt * 16 + (ll & 15);
        W1f[i] = f2bf(W1[k * 64 + col]);
    }
    __syncthreads();

    short8 w1r[8][4];
    const short8* wf = (const short8*)W1f;
#pragma unroll
    for (int c = 0; c < 8; ++c)
#pragma unroll
        for (int nt = 0; nt < 4; ++nt)
            w1r[c][nt] = wf[(c * 4 + nt) * 64 + l];

    short8 w2r[2];
#pragma unroll
    for (int c = 0; c < 2; ++c) {
        U8 t8;
#pragma unroll
        for (int m = 0; m < 4; ++m) {
            int k0 = c * 32 + lg * 8 + 2 * m;
            t8.u[m] = cvt_pk_bf16(W2[k0 * 16 + li], W2[(k0 + 1) * 16 + li]);
        }
        w2r[c] = t8.s8;
    }

    float b1v[4];
#pragma unroll
    for (int nt = 0; nt < 4; ++nt) b1v[nt] = b1[nt * 16 + li];
    const float b2v = b2[li];
    const float w3v = W3[li];
    const float b3r = b3[0];

    const float* qp = target + (size_t)b * 64;
    float qf_lo[8], qf_hi[8];
#pragma unroll
    for (int j = 0; j < 8; ++j) { qf_lo[j] = qp[lg * 8 + j]; qf_hi[j] = qp[32 + lg * 8 + j]; }
    U8 q8l, q8h;
#pragma unroll
    for (int m = 0; m < 4; ++m) {
        q8l.u[m] = cvt_pk_bf16(qf_lo[2 * m], qf_lo[2 * m + 1]);
        q8h.u[m] = cvt_pk_bf16(qf_hi[2 * m], qf_hi[2 * m + 1]);
    }

    for (int mt = wv; mt * 16 < len; mt += 4) {
        const int t = mt * 16 + li;
        const int tld = (t < TT) ? t : TT - 1;
        const unsigned short* hp = seq_hb + ((size_t)b * TT + tld) * 64 + lg * 8;
        short8 h8l = *(const short8*)hp;
        short8 h8h = *(const short8*)(hp + 32);

        U8 d8l, d8h, m8l, m8h;
#pragma unroll
        for (int m = 0; m < 4; ++m) {
            float h0, h1, d0, d1, p0, p1;
            h0 = bf2f((unsigned short)h8l[2 * m]); h1 = bf2f((unsigned short)h8l[2 * m + 1]);
            d0 = qf_lo[2 * m] - h0; d1 = qf_lo[2 * m + 1] - h1;
            p0 = qf_lo[2 * m] * h0; p1 = qf_lo[2 * m + 1] * h1;
            d8l.u[m] = cvt_pk_bf16(d0, d1);
            m8l.u[m] = cvt_pk_bf16(p0, p1);
            h0 = bf2f((unsigned short)h8h[2 * m]); h1 = bf2f((unsigned short)h8h[2 * m + 1]);
            d0 = qf_hi[2 * m] - h0; d1 = qf_hi[2 * m + 1] - h1;
            p0 = qf_hi[2 * m] * h0; p1 = qf_hi[2 * m + 1] * h1;
            d8h.u[m] = cvt_pk_bf16(d0, d1);
            m8h.u[m] = cvt_pk_bf16(p0, p1);
        }

        f32x4 acc[4];
#pragma unroll
        for (int nt = 0; nt < 4; ++nt) acc[nt] = (f32x4){0.f, 0.f, 0.f, 0.f};
#pragma unroll
        for (int nt = 0; nt < 4; ++nt) {
            acc[nt] = __builtin_amdgcn_mfma_f32_16x16x32_bf16(q8l.s8, w1r[0][nt], acc[nt], 0, 0, 0);
            acc[nt] = __builtin_amdgcn_mfma_f32_16x16x32_bf16(q8h.s8, w1r[1][nt], acc[nt], 0, 0, 0);
            acc[nt] = __builtin_amdgcn_mfma_f32_16x16x32_bf16(h8l,    w1r[2][nt], acc[nt], 0, 0, 0);
            acc[nt] = __builtin_amdgcn_mfma_f32_16x16x32_bf16(h8h,    w1r[3][nt], acc[nt], 0, 0, 0);
            acc[nt] = __builtin_amdgcn_mfma_f32_16x16x32_bf16(d8l.s8, w1r[4][nt], acc[nt], 0, 0, 0);
            acc[nt] = __builtin_amdgcn_mfma_f32_16x16x32_bf16(d8h.s8, w1r[5][nt], acc[nt], 0, 0, 0);
            acc[nt] = __builtin_amdgcn_mfma_f32_16x16x32_bf16(m8l.s8, w1r[6][nt], acc[nt], 0, 0, 0);
            acc[nt] = __builtin_amdgcn_mfma_f32_16x16x32_bf16(m8h.s8, w1r[7][nt], acc[nt], 0, 0, 0);
        }

#pragma unroll
        for (int nt = 0; nt < 4; ++nt)
#pragma unroll
            for (int jj = 0; jj < 4; ++jj) {
                float v = acc[nt][jj] + b1v[nt];
                a1s[wv][lg * 4 + jj][nt * 16 + li] = (v > 0.f) ? v : 0.25f * v;
            }

        const float* arow = &a1s[wv][li][0];
        f32x4 acc2 = (f32x4){0.f, 0.f, 0.f, 0.f};
#pragma unroll
        for (int c2 = 0; c2 < 2; ++c2) {
            f32x4 v0 = *(const f32x4*)(arow + c2 * 32 + lg * 8);
            f32x4 v1 = *(const f32x4*)(arow + c2 * 32 + lg * 8 + 4);
            U8 a2f;
            a2f.u[0] = cvt_pk_bf16(v0[0], v0[1]);
            a2f.u[1] = cvt_pk_bf16(v0[2], v0[3]);
            a2f.u[2] = cvt_pk_bf16(v1[0], v1[1]);
            a2f.u[3] = cvt_pk_bf16(v1[2], v1[3]);
            acc2 = __builtin_amdgcn_mfma_f32_16x16x32_bf16(a2f.s8, w2r[c2], acc2, 0, 0, 0);
        }

#pragma unroll
        for (int jj = 0; jj < 4; ++jj) {
            float a2 = acc2[jj] + b2v;
            a2 = (a2 > 0.f) ? a2 : 0.25f * a2;
            float part = a2 * w3v;
            part += __shfl_xor(part, 1);
            part += __shfl_xor(part, 2);
            part += __shfl_xor(part, 4);
            part += __shfl_xor(part, 8);
            int tt = mt * 16 + lg * 4 + jj;
            if (li == 0 && tt < TT)
                logit_lds[tt] = (tt < len) ? (part + b3r) : -1e9f;
        }
    }
    __syncthreads();

    float v = (tid < TT) ? logit_lds[tid] : -1e30f;
    float m = v;
#pragma unroll
    for (int s = 1; s < 64; s <<= 1) m = fmaxf(m, __shfl_xor(m, s));
    if (l == 0) red[wv] = m;
    __syncthreads();
    m = fmaxf(fmaxf(red[0], red[1]), fmaxf(red[2], red[3]));
    float e = (tid < TT) ? __expf(v - m) : 0.f;
    float sum = e;
#pragma unroll
    for (int s = 1; s < 64; s <<= 1) sum += __shfl_xor(sum, s);
    if (l == 0) red[4 + wv] = sum;
    __syncthreads();
    float inv = __fdividef(1.f, red[4] + red[5] + red[6] + red[7]);
    if (tid < TT) scores[(size_t)b * TT + tid] = e * inv;
}

// ---------------------------------------------------------------------------
// FFN chain (tiny, unchanged)
// ---------------------------------------------------------------------------
__global__ __launch_bounds__(256) void k_fc1(const float* __restrict__ fin,
                                             const float* __restrict__ tgt,
                                             const float* __restrict__ oth,
                                             const float* __restrict__ Wt,
                                             const float* __restrict__ bvec,
                                             float* __restrict__ fout) {
    __shared__ float z0[164];
    int b = blockIdx.x, tid = threadIdx.x;
    if (tid < 64) z0[tid] = fin[b * 64 + tid];
    else if (tid < 128) z0[tid] = tgt[b * 64 + tid - 64];
    else if (tid < 164) z0[tid] = oth[b * 36 + tid - 128];
    __syncthreads();
    float acc = bvec[tid];
#pragma unroll 4
    for (int k = 0; k < 164; ++k) acc += z0[k] * Wt[k * 256 + tid];
    fout[(size_t)b * 256 + tid] = acc;
}

template <int F>
__global__ __launch_bounds__(256) void k_stats(const float* __restrict__ x, float* __restrict__ stat) {
    int c = blockIdx.x, tid = threadIdx.x;
    float s = 0.f, sq = 0.f;
    for (int i = tid; i < BB; i += 256) {
        float v = x[(size_t)i * F + c];
        s += v; sq += v * v;
    }
#pragma unroll
    for (int m = 1; m < 64; m <<= 1) { s += __shfl_xor(s, m); sq += __shfl_xor(sq, m); }
    __shared__ float rs[4], rq[4];
    if ((tid & 63) == 0) { rs[tid >> 6] = s; rq[tid >> 6] = sq; }
    __syncthreads();
    if (tid == 0) {
        float S = rs[0] + rs[1] + rs[2] + rs[3];
        float Q = rq[0] + rq[1] + rq[2] + rq[3];
        float mean = S * (1.f / BB);
        float var = Q * (1.f / BB) - mean * mean;
        stat[c] = mean;
        stat[F + c] = var;
    }
}

__global__ __launch_bounds__(256) void k_fc2(const float* __restrict__ f1,
                                             const float* __restrict__ st1,
                                             const float* __restrict__ Wt,
                                             const float* __restrict__ bvec,
                                             float* __restrict__ f2) {
    __shared__ float z[256];
    int b = blockIdx.x, tid = threadIdx.x;
    float x = f1[(size_t)b * 256 + tid];
    z[tid] = dicef_(x, st1[tid], st1[256 + tid]);
    __syncthreads();
    if (tid < 128) {
        float acc = bvec[tid];
#pragma unroll 4
        for (int k = 0; k < 256; ++k) acc += z[k] * Wt[k * 128 + tid];
        f2[(size_t)b * 128 + tid] = acc;
    }
}

__global__ __launch_bounds__(128) void k_fc3(const float* __restrict__ f2,
                                             const float* __restrict__ st2,
                                             const float* __restrict__ Wt,
                                             const float* __restrict__ bvec,
                                             float* __restrict__ f3) {
    __shared__ float z[128];
    int b = blockIdx.x, tid = threadIdx.x;
    float x = f2[(size_t)b * 128 + tid];
    z[tid] = dicef_(x, st2[tid], st2[128 + tid]);
    __syncthreads();
    if (tid < 64) {
        float acc = bvec[tid];
#pragma unroll 4
        for (int k = 0; k < 128; ++k) acc += z[k] * Wt[k * 64 + tid];
        f3[(size_t)b * 64 + tid] = acc;
    }
}

__global__ void k_out(const float* __restrict__ f3, const float* __restrict__ st3,
                      const float* __restrict__ outW, const float* __restrict__ outb,
                      float* __restrict__ out) {
    int b = blockIdx.x, l = threadIdx.x;  // 64 threads
    float x = f3[(size_t)b * 64 + l];
    float z = dicef_(x, st3[l], st3[64 + l]);
    float p = z * outW[l];
#pragma unroll
    for (int m = 1; m < 64; m <<= 1) p += __shfl_xor(p, m);
    if (l == 0) out[b] = sigmoidf_(p + outb[0]);
}

// ---------------------------------------------------------------------------
extern "C" void kernel_launch(void* const* d_in, const int* in_sizes, int n_in,
                              void* d_out, int out_size, void* d_ws, size_t ws_size,
                              hipStream_t stream) {
    const float* dense      = (const float*)d_in[0];
    const int*   sparse     = (const int*)d_in[1];
    const int*   seq_idx    = (const int*)d_in[2];
    const int*   item_idx   = (const int*)d_in[3];
    const int*   hist_len   = (const int*)d_in[4];
    const float* item_table = (const float*)d_in[5];
    const float* other_tab  = (const float*)d_in[6];
    const float* gru_W = (const float*)d_in[7];
    const float* gru_U = (const float*)d_in[8];
    const float* gru_b = (const float*)d_in[9];
    const float* aug_W = (const float*)d_in[10];
    const float* aug_U = (const float*)d_in[11];
    const float* aug_b = (const float*)d_in[12];
    const float* att_W1 = (const float*)d_in[13];
    const float* att_b1 = (const float*)d_in[14];
    const float* att_W2 = (const float*)d_in[15];
    const float* att_b2 = (const float*)d_in[16];
    const float* att_W3 = (const float*)d_in[17];
    const float* att_b3 = (const float*)d_in[18];
    const float* ffn_W1 = (const float*)d_in[19];
    const float* ffn_b1 = (const float*)d_in[20];
    const float* ffn_W2 = (const float*)d_in[21];
    const float* ffn_b2 = (const float*)d_in[22];
    const float* ffn_W3 = (const float*)d_in[23];
    const float* ffn_b3 = (const float*)d_in[24];
    const float* out_W  = (const float*)d_in[25];
    const float* out_b  = (const float*)d_in[26];

    float* wsf = (float*)d_ws;
    unsigned short* xwb   = (unsigned short*)(wsf);              // (B*T,192) bf16
    unsigned short* seqhb = (unsigned short*)(wsf + 19660800);   // (B,T,64) bf16
    float* scores = wsf + 26214400;            // B*T
    float* target = wsf + 26419200;            // B*64
    float* other  = wsf + 26484736;            // B*36
    float* finals = wsf + 26521600;            // B*64
    float* f1     = wsf + 26587136;            // B*256
    float* f2     = wsf + 26849280;            // B*128
    float* f3     = wsf + 26980352;            // B*64
    float* st1    = wsf + 27045888;            // 512
    float* st2    = wsf + 27046400;            // 256
    float* st3    = wsf + 27046656;            // 128

    float* dout = (float*)d_out;
    const int Mtiles = (BB * TT) / 16;  // 12800

    k_prep<<<BB, 64, 0, stream>>>(dense, sparse, item_idx, item_table, other_tab, target, other);

    // xw1 = gather(item_table, seq_idx) @ gru_W + gru_b  (bf16 MFMA, masked tiles skipped)
    k_xw<1><<<800, 256, 0, stream>>>(seq_idx, item_table, nullptr, gru_W, gru_b, hist_len, xwb, Mtiles, 3200);

    // GRU1 recurrence -> seq_h bf16 (B,T,64)   [1 wave/row, LDS U, depth-4 prefetch]
    k_scan11<0><<<BB, 64, 0, stream>>>(xwb, gru_U, hist_len, scores, seqhb, finals);

    // attention MLP (MFMA) + fused softmax -> scores
    k_att<<<BB, 256, 0, stream>>>(target, seqhb, att_W1, att_b1, att_W2, att_b2,
                                  att_W3, att_b3, hist_len, scores);

    // xw2 = seq_h @ aug_W + aug_b  (bf16 MFMA, masked tiles skipped)
    k_xw<0><<<800, 256, 0, stream>>>(nullptr, nullptr, seqhb, aug_W, aug_b, hist_len, xwb, Mtiles, 3200);

    // AUGRU recurrence -> finals f32 (B,64)
    k_scan11<1><<<BB, 64, 0, stream>>>(xwb, aug_U, hist_len, scores, seqhb, finals);

    k_fc1<<<BB, 256, 0, stream>>>(finals, target, other, ffn_W1, ffn_b1, f1);
    k_stats<256><<<256, 256, 0, stream>>>(f1, st1);
    k_fc2<<<BB, 256, 0, stream>>>(f1, st1, ffn_W2, ffn_b2, f2);
    k_stats<128><<<128, 256, 0, stream>>>(f2, st2);
    k_fc3<<<BB, 128, 0, stream>>>(f2, st2, ffn_W3, ffn_b3, f3);
    k_stats<64><<<64, 256, 0, stream>>>(f3, st3);
    k_out<<<BB, 64, 0, stream>>>(f3, st3, out_W, out_b, dout);
}